// Round 14
// baseline (518.293 us; speedup 1.0000x reference)
//
#include <hip/hip_runtime.h>
#include <math.h>

// Problem constants
#define CL 2
#define CH 12
#define CD 768
#define CDH 64
#define CF 3072
#define CB 2
#define CT 2048
#define CBH (CB * CH)
#define CBTCD ((size_t)CB * CT * CD)

typedef __bf16 bf16x8 __attribute__((ext_vector_type(8)));
typedef float f32x4 __attribute__((ext_vector_type(4)));
typedef short s16x4 __attribute__((ext_vector_type(4)));
typedef ushort u16x4 __attribute__((ext_vector_type(4)));

// 0.125 * log2(e): folded into Wq/bq so QK^T lands in exp2 domain
#define QSCALE 0.18033688011112042f

__device__ __forceinline__ ushort f2bf(float f) {
  return __builtin_bit_cast(ushort, (__bf16)f);
}

__device__ __forceinline__ float fexp2(float x) {
  float r;
  asm volatile("v_exp_f32 %0, %1" : "=v"(r) : "v"(x));
  return r;
}

__device__ __forceinline__ float wred_sum(float v) {
#pragma unroll
  for (int o = 32; o > 0; o >>= 1) v += __shfl_xor(v, o);
  return v;
}

// async global->LDS, 16B per lane. LDS dest = wave-uniform base + lane*16.
__device__ __forceinline__ void gload16(const ushort* g, ushort* l) {
  __builtin_amdgcn_global_load_lds(
      (const __attribute__((address_space(1))) unsigned int*)g,
      (__attribute__((address_space(3))) unsigned int*)l, 16, 0, 0);
}

// ---------------- GEMM (m97 structure, 3-buffer 1-deep prefetch,
//          SINGLE barrier per K-step, XCD swizzle, BN=128 or 256) ----------
// C(MxN) = A(MxK) @ B, A bf16 row-major (lda), B stored (N x K) row-major (ldb).
// REQUIRES: M % 128 == 0, N % BN == 0, K % 64 == 0, (gridX*gridY) % 8 == 0.
// Single-barrier safety (N=3 buffers, D=1 prefetch): D+1=2 !≡ 0 (mod 3).
// BN=256: wave tile 64x128 -> 6 B/lane/MFMA LDS-read (vs 8 at BN=128),
// +33% FLOP per LDS byte on the LDS-read-bound pipe; 72 KB LDS, 2 blocks/CU.
enum { EPI_BF16 = 1, EPI_BIAS_BF16 = 2, EPI_BIAS_GELU_BF16 = 3, EPI_BIAS_RES_F32 = 4, EPI_BIAS_RES_F32_BF16 = 5, EPI_PART_F32 = 6, EPI_QKV = 7 };

template <int EPI, int BN>
__global__ __launch_bounds__(256) void gemm_k(
    const ushort* __restrict__ A, int lda,
    const ushort* __restrict__ B, int ldb,
    void* __restrict__ Cv, int ldc,
    int K,
    const float* __restrict__ bias,
    const float* __restrict__ res,
    ushort* __restrict__ C2) {
  constexpr int NB = BN / 32;       // B frags per wave (4 or 8)
  constexpr int BISS = BN / 64;     // B stage issues (2 or 4)
  __shared__ ushort As[3][128 * 32];
  __shared__ ushort Bs[3][BN * 32];
  const int tid = threadIdx.x;
  const int lane = tid & 63;
  const int wave = tid >> 6;
  const int wm = (wave >> 1) * 64;
  const int wn = (wave & 1) * (BN / 2);

  // bijective XCD swizzle (gridX*gridY multiple of 8)
  const int gx = gridDim.x;
  const int nwg = gx * gridDim.y;
  int wgid = blockIdx.y * gx + blockIdx.x;
  const int cpx = nwg >> 3;
  wgid = (wgid & 7) * cpx + (wgid >> 3);
  const int m0 = (wgid / gx) * 128;
  const int n0 = (wgid % gx) * BN;

  const int lr = lane & 15;
  const int lg = lane >> 4;
  f32x4 acc[4][NB] = {};

  const int kz = blockIdx.z * K;  // K-split offset (0 for non-split launches)
  const ushort* pa = A + (size_t)(m0 + (tid >> 2)) * lda + (tid & 3) * 8 + kz;
  const ushort* pb = B + (size_t)(n0 + (tid >> 2)) * ldb + (tid & 3) * 8 + kz;

  auto stage = [&](int buf, int k0) {
#pragma unroll
    for (int p = 0; p < 2; ++p)
      gload16(pa + (size_t)p * 64 * lda + k0, &As[buf][wave * 512 + p * 2048]);
#pragma unroll
    for (int p = 0; p < BISS; ++p)
      gload16(pb + (size_t)p * 64 * ldb + k0, &Bs[buf][wave * 512 + p * 2048]);
  };

  const int nt = K >> 5;
  stage(0, 0);
  for (int kt = 0; kt < nt; ++kt) {
    const int cur = kt % 3;
    if (kt + 1 < nt) {
      stage((kt + 1) % 3, (kt + 1) << 5);
      if constexpr (BN == 128)
        asm volatile("s_waitcnt vmcnt(4)" ::: "memory");
      else
        asm volatile("s_waitcnt vmcnt(6)" ::: "memory");
    } else {
      asm volatile("s_waitcnt vmcnt(0)" ::: "memory");
    }
    __builtin_amdgcn_s_barrier();
    __builtin_amdgcn_sched_barrier(0);

    bf16x8 af[4], bfr[NB];
#pragma unroll
    for (int f = 0; f < 4; ++f) af[f] = *(const bf16x8*)(&As[cur][(wm + f * 16 + lr) * 32 + lg * 8]);
#pragma unroll
    for (int f = 0; f < NB; ++f) bfr[f] = *(const bf16x8*)(&Bs[cur][(wn + f * 16 + lr) * 32 + lg * 8]);
#pragma unroll
    for (int i = 0; i < 4; ++i)
#pragma unroll
      for (int j = 0; j < NB; ++j)
        acc[i][j] = __builtin_amdgcn_mfma_f32_16x16x32_bf16(af[i], bfr[j], acc[i][j], 0, 0, 0);
  }

  // epilogue: lane holds D[row=(lane>>4)*4+r][col=lane&15] per frag
  const int cr0 = lg * 4;
#pragma unroll
  for (int i = 0; i < 4; ++i) {
#pragma unroll
    for (int j = 0; j < NB; ++j) {
      int col = n0 + wn + j * 16 + lr;
      if constexpr (EPI == EPI_QKV) {
        const int cbase = n0 + wn + j * 16;  // frag col base (uniform)
        const int row0 = m0 + wm + i * 16 + cr0;
        float bcol = bias[col];
        if (cbase >= 2 * CD) {
          // V section: write ONLY transposed vt[bh][e][t], 4 tokens = u16x4
          const int bb = row0 >> 11;          // row0 / CT
          const int t0 = row0 & (CT - 1);
          const int hh = (cbase - 2 * CD) >> 6;
          const int ee = ((cbase - 2 * CD) & 63) + lr;
          u16x4 o;
#pragma unroll
          for (int r = 0; r < 4; ++r) o[r] = f2bf(acc[i][j][r] + bcol);
          *(u16x4*)(C2 + ((size_t)(bb * CH + hh) * 64 + ee) * CT + t0) = o;
        } else {
#pragma unroll
          for (int r = 0; r < 4; ++r)
            ((ushort*)Cv)[(size_t)(row0 + r) * ldc + col] = f2bf(acc[i][j][r] + bcol);
        }
        continue;
      }
#pragma unroll
      for (int r = 0; r < 4; ++r) {
        int row = m0 + wm + i * 16 + cr0 + r;
        float val = acc[i][j][r];
        size_t offc = (size_t)row * ldc + col;
        if constexpr (EPI == EPI_BF16) {
          ((ushort*)Cv)[offc] = f2bf(val);
        } else if constexpr (EPI == EPI_BIAS_BF16) {
          ((ushort*)Cv)[offc] = f2bf(val + bias[col]);
        } else if constexpr (EPI == EPI_BIAS_GELU_BF16) {
          float x = val + bias[col];
          float gel = 0.5f * x * (1.0f + erff(x * 0.70710678118654752f));
          ((ushort*)Cv)[offc] = f2bf(gel);
        } else if constexpr (EPI == EPI_BIAS_RES_F32) {
          ((float*)Cv)[offc] = val + bias[col] + res[offc];
        } else if constexpr (EPI == EPI_PART_F32) {
          ((float*)Cv)[blockIdx.z * CBTCD + offc] = val;
        } else if constexpr (EPI == EPI_BIAS_RES_F32_BF16) {
          float o = val + bias[col] + res[offc];
          ((float*)Cv)[offc] = o;
          C2[offc] = f2bf(o);
        }
      }
    }
  }
}

// ---------------- split-K reduce: out = p0 + p1 + bias + res ----------------
template <bool DUAL>
__global__ __launch_bounds__(256) void reduce2_k(const float* __restrict__ part,
                                                 const float* __restrict__ bias,
                                                 const float* __restrict__ res,
                                                 float* __restrict__ outf,
                                                 ushort* __restrict__ outb) {
  int i = blockIdx.x * 256 + threadIdx.x;  // float4 index over 4096x768
  float4 p0 = ((const float4*)part)[i];
  float4 p1 = ((const float4*)(part + CBTCD))[i];
  float4 rr = ((const float4*)res)[i];
  int col = (i * 4) % CD;
  float4 bb = *(const float4*)(bias + col);
  float4 o;
  o.x = p0.x + p1.x + rr.x + bb.x;
  o.y = p0.y + p1.y + rr.y + bb.y;
  o.z = p0.z + p1.z + rr.z + bb.z;
  o.w = p0.w + p1.w + rr.w + bb.w;
  ((float4*)outf)[i] = o;
  if constexpr (DUAL) {
    ushort4 u;
    u.x = f2bf(o.x); u.y = f2bf(o.y); u.z = f2bf(o.z); u.w = f2bf(o.w);
    ((ushort4*)outb)[i] = u;
  }
}

// ---------------- flash attention (swapped QK^T, in-register softmax,
//   T14 reg-prefetch, dbuf LDS, 1 barrier/tile, XOR-swizzled LDS slots,
//   ZERO-SHFL hot path + st-hoisted-above-compute) ----------------
// grid: (CT/64, CB*CH). block 256 = 4 waves; each wave owns 16 q rows (q=lr).
__global__ __launch_bounds__(256) void flash_k(const ushort* __restrict__ qkv,
                                               const ushort* __restrict__ vt,
                                               const unsigned* __restrict__ mbits,
                                               const unsigned char* __restrict__ rowall,
                                               ushort* __restrict__ out) {
  const int q0 = blockIdx.x * 64;
  const int bh = blockIdx.y;
  const int b = bh / CH, h = bh % CH;
  const int tid = threadIdx.x;
  const int lane = tid & 63;
  const int wave = tid >> 6;
  const int lr = lane & 15;
  const int lg = lane >> 4;

  __shared__ ushort Ks[2][64 * 64];   // [buf][kv][d] swizzled slots
  __shared__ ushort Vt[2][64 * 64];   // [buf][e][kv] swizzled slots

  const int qg = q0 + wave * 16 + lr;  // this lane's q row
  const ushort* qrow = qkv + ((size_t)(b * CT) + qg) * 2304 + h * CDH;
  bf16x8 aq0 = *(const bf16x8*)(qrow + lg * 8);
  bf16x8 aq1 = *(const bf16x8*)(qrow + 32 + lg * 8);

  f32x4 acc[4] = {};              // O^T frags: acc[jj][r] = O^T[jj*16+lg*4+r][q=lr]
  float m_run = -1e30f, l_run = 0.f;  // l_run: per-LANE partial (mates share m)
  const bool am = rowall[qg] != 0;    // row fully unmasked -> skip mask work

  const ushort* kbase = qkv + (size_t)(b * CT) * 2304 + CD + h * CDH;
  const ushort* vbase = vt + (size_t)bh * 64 * CT;

  // staging: rows r0/r1 (r1 = r0+32 -> same (row&7)), global col cc LINEAR,
  // LDS slot swizzled: ssl = (slot ^ (r0&7)) * 8 elements
  const int r0 = tid >> 3, r1 = 32 + (tid >> 3), cc = (tid & 7) * 8;
  const int ssl = (((tid & 7) ^ (r0 & 7)) * 8);

  // swizzled READ offsets (elements)
  const int koff0 = ((lg ^ (lr & 7)) * 8);        // K d-half 0: slot lg
  const int koff1 = (((4 + lg) ^ (lr & 7)) * 8);  // K d-half 1: slot 4+lg
  int voff[4];
#pragma unroll
  for (int j = 0; j < 4; ++j)
    voff[j] = (((2 * j + (lg >> 1)) ^ (lr & 7)) * 8) + (lg & 1) * 4;

  auto ld = [&](int kv0, bf16x8& k0, bf16x8& k1, bf16x8& v0, bf16x8& v1) {
    k0 = *(const bf16x8*)(kbase + (size_t)(kv0 + r0) * 2304 + cc);
    k1 = *(const bf16x8*)(kbase + (size_t)(kv0 + r1) * 2304 + cc);
    v0 = *(const bf16x8*)(vbase + (size_t)r0 * CT + kv0 + cc);
    v1 = *(const bf16x8*)(vbase + (size_t)r1 * CT + kv0 + cc);
  };
  auto st = [&](int buf, bf16x8 k0, bf16x8 k1, bf16x8 v0, bf16x8 v1) {
    *(bf16x8*)(&Ks[buf][r0 * 64 + ssl]) = k0;
    *(bf16x8*)(&Ks[buf][r1 * 64 + ssl]) = k1;
    *(bf16x8*)(&Vt[buf][r0 * 64 + ssl]) = v0;
    *(bf16x8*)(&Vt[buf][r1 * 64 + ssl]) = v1;
  };
  // lgkmcnt-only barrier: ds_writes visible, global prefetch stays in flight
  auto bar = [&]() {
    asm volatile("s_waitcnt lgkmcnt(0)" ::: "memory");
    __builtin_amdgcn_s_barrier();
    __builtin_amdgcn_sched_barrier(0);
  };

  auto compute = [&](int kv0, int buf) {
    // S^T = K Q^T (4 tiles of 16 kv x 16 q), already exp2-domain scaled
    f32x4 stt[4];
    __builtin_amdgcn_s_setprio(1);
#pragma unroll
    for (int j = 0; j < 4; ++j) {
      bf16x8 kf0 = *(const bf16x8*)(&Ks[buf][(j * 16 + lr) * 64 + koff0]);
      bf16x8 kf1 = *(const bf16x8*)(&Ks[buf][(j * 16 + lr) * 64 + koff1]);
      f32x4 t = {};
      t = __builtin_amdgcn_mfma_f32_16x16x32_bf16(kf0, aq0, t, 0, 0, 0);
      t = __builtin_amdgcn_mfma_f32_16x16x32_bf16(kf1, aq1, t, 0, 0, 0);
      stt[j] = t;
    }
    __builtin_amdgcn_s_setprio(0);

    // mask + IN-LANE max over this lane's 16 kv values (rowall hot path)
    float tmax = -INFINITY;
    if (am) {
#pragma unroll
      for (int j = 0; j < 4; ++j)
#pragma unroll
        for (int r = 0; r < 4; ++r) tmax = fmaxf(tmax, stt[j][r]);
    } else {
      unsigned w0 = mbits[(size_t)qg * 64 + (kv0 >> 5)];
      unsigned w1 = mbits[(size_t)qg * 64 + (kv0 >> 5) + 1];
#pragma unroll
      for (int j = 0; j < 4; ++j) {
        unsigned w = (j < 2) ? w0 : w1;
#pragma unroll
        for (int r = 0; r < 4; ++r) {
          int bit = (j * 16 + lg * 4 + r) & 31;
          if (((w >> bit) & 1u) == 0u) stt[j][r] = -INFINITY;
          tmax = fmaxf(tmax, stt[j][r]);
        }
      }
    }

    // defer-rescale (T13) with ZERO-SHFL hot path: __any over LANE-local max
    // is equivalent to testing the row max. The cross-lane max (2 shfls)
    // runs only inside the rescale branch where it is actually needed.
    if (__any(tmax - m_run > 8.0f)) {
      tmax = fmaxf(tmax, __shfl_xor(tmax, 16));
      tmax = fmaxf(tmax, __shfl_xor(tmax, 32));
      float mnew = fmaxf(m_run, tmax);
      float sc = fexp2(m_run - mnew);
      m_run = mnew;
      l_run *= sc;
#pragma unroll
      for (int jj = 0; jj < 4; ++jj) {
        acc[jj][0] *= sc; acc[jj][1] *= sc; acc[jj][2] *= sc; acc[jj][3] *= sc;
      }
    }

    s16x4 pf[4];
#pragma unroll
    for (int j = 0; j < 4; ++j) {
      s16x4 pv;
#pragma unroll
      for (int r = 0; r < 4; ++r) {
        float p = fexp2(stt[j][r] - m_run);
        l_run += p;
        pv[r] = (short)f2bf(p);
      }
      pf[j] = pv;
    }

    // PV: O^T[e][q] += V^T[e][kv] * P^T[kv][q], 16x16x16 mfma, K=16 per j
    __builtin_amdgcn_s_setprio(1);
#pragma unroll
    for (int jj = 0; jj < 4; ++jj) {
#pragma unroll
      for (int j = 0; j < 4; ++j) {
        s16x4 vf = *(const s16x4*)(&Vt[buf][(jj * 16 + lr) * 64 + voff[j]]);
        acc[jj] = __builtin_amdgcn_mfma_f32_16x16x16bf16_1k(vf, pf[j], acc[jj], 0, 0, 0);
      }
    }
    __builtin_amdgcn_s_setprio(0);
  };

  // main loop: dbuf LDS, ONE barrier per tile, reg ping-pong X/Y prefetch.
  // st() is hoisted ABOVE compute() — the ds_writes drain under the MFMA
  // cluster. Safety: each st(buf) still sits after the barrier that retired
  // buf's last reader (st(1) after loop-end bar; st(0) after mid bar).
  bf16x8 kx0, kx1, vx0, vx1, ky0, ky1, vy0, vy1;
  ld(0, kx0, kx1, vx0, vx1);
  ld(64, ky0, ky1, vy0, vy1);
  st(0, kx0, kx1, vx0, vx1);
  bar();
  for (int t = 0; t < 32; t += 2) {
    if (t + 2 < 32) ld((t + 2) * 64, kx0, kx1, vx0, vx1);
    st(1, ky0, ky1, vy0, vy1);
    compute(t * 64, 0);
    bar();
    if (t + 3 < 32) ld((t + 3) * 64, ky0, ky1, vy0, vy1);
    if (t + 2 < 32) st(0, kx0, kx1, vx0, vx1);
    compute((t + 1) * 64, 1);
    if (t + 2 < 32) bar();
  }

  // final cross-lane reduce of per-lane l partials (mates lr, +16, +32, +48)
  l_run += __shfl_xor(l_run, 16);
  l_run += __shfl_xor(l_run, 32);

  // write O: lane holds O^T[e=jj*16+lg*4+r][q=lr] -> out[qg][h*64+e]
  float inv = 1.0f / l_run;
  const int orow = b * CT + qg;
#pragma unroll
  for (int jj = 0; jj < 4; ++jj) {
    u16x4 o;
#pragma unroll
    for (int r = 0; r < 4; ++r) o[r] = f2bf(acc[jj][r] * inv);
    *(u16x4*)(out + (size_t)orow * CD + h * CDH + jj * 16 + lg * 4) = o;
  }
}

// ---------------- mask -> bitmask + per-row all-ones flag (fused) ----------
// block 256 = 4 waves; wave w handles row t = blockIdx.x*4 + w, lane = word.
__global__ __launch_bounds__(256) void maskrow_k(const int* __restrict__ mask,
                                                 unsigned* __restrict__ mbits,
                                                 unsigned char* __restrict__ rowall) {
  const int lane = threadIdx.x & 63;
  const int t = blockIdx.x * 4 + (threadIdx.x >> 6);
  const int* mp = mask + (size_t)t * CT + lane * 32;
  unsigned bits = 0;
#pragma unroll
  for (int j = 0; j < 32; ++j) bits |= (mp[j] != 0 ? 1u : 0u) << j;
  mbits[(size_t)t * 64 + lane] = bits;
  unsigned long long vote = __ballot(bits == 0xFFFFFFFFu);
  if (lane == 0) rowall[t] = (vote == ~0ull) ? 1 : 0;
}

// ---------------- layernorm ----------------
__global__ __launch_bounds__(256) void ln_k(const float* __restrict__ X,
                                            ushort* __restrict__ H,
                                            const float* __restrict__ g,
                                            const float* __restrict__ b) {
  const int t = blockIdx.x;
  const int tid = threadIdx.x;
  const float* row = X + (size_t)t * CD;
  float x0 = row[tid], x1 = row[tid + 256], x2 = row[tid + 512];
  float s = wred_sum(x0 + x1 + x2);
  __shared__ float sh[4], sh2[4];
  if ((tid & 63) == 0) sh[tid >> 6] = s;
  __syncthreads();
  float mu = (sh[0] + sh[1] + sh[2] + sh[3]) * (1.0f / 768.0f);
  float d0 = x0 - mu, d1 = x1 - mu, d2 = x2 - mu;
  float vs = wred_sum(d0 * d0 + d1 * d1 + d2 * d2);
  if ((tid & 63) == 0) sh2[tid >> 6] = vs;
  __syncthreads();
  float var = (sh2[0] + sh2[1] + sh2[2] + sh2[3]) * (1.0f / 768.0f);
  float r = 1.0f / sqrtf(var + 1e-5f);
  H[(size_t)t * CD + tid] = f2bf(d0 * r * g[tid] + b[tid]);
  H[(size_t)t * CD + tid + 256] = f2bf(d1 * r * g[tid + 256] + b[tid + 256]);
  H[(size_t)t * CD + tid + 512] = f2bf(d2 * r * g[tid + 512] + b[tid + 512]);
}

// ---------------- conversions / repacks ----------------
__global__ void f32_to_bf16_k(const float* __restrict__ in, ushort* __restrict__ out, int n4) {
  int i = blockIdx.x * 256 + threadIdx.x;
  if (i >= n4) return;
  float4 f = *(const float4*)(in + (size_t)i * 4);
  ushort4 u;
  u.x = f2bf(f.x); u.y = f2bf(f.y); u.z = f2bf(f.z); u.w = f2bf(f.w);
  *(ushort4*)(out + (size_t)i * 4) = u;
}

// tiled transpose + f32->bf16: src (z batches, [R][C] f32, stride sbs) ->
// dst (z batches, [C][R] bf16, stride dbs). R, C multiples of 32.
__global__ __launch_bounds__(256) void tcvt_k(const float* __restrict__ src, size_t sbs,
                                              ushort* __restrict__ dst, size_t dbs,
                                              int R, int C, float scale) {
  __shared__ float t[32][33];
  const float* s = src + blockIdx.z * sbs;
  ushort* d = dst + blockIdx.z * dbs;
  const int tx = threadIdx.x & 31;
  const int ty4 = (threadIdx.x >> 5) * 4;
  const int r0 = blockIdx.y * 32, c0 = blockIdx.x * 32;
#pragma unroll
  for (int i = 0; i < 4; ++i) t[ty4 + i][tx] = s[(size_t)(r0 + ty4 + i) * C + c0 + tx];
  __syncthreads();
#pragma unroll
  for (int i = 0; i < 4; ++i)
    d[(size_t)(c0 + ty4 + i) * R + r0 + tx] = f2bf(t[tx][ty4 + i] * scale);
}

// bq/bk/bv (L,H,DH) -> bqkv (L, 2304) fp32; bq scaled by QSCALE
__global__ void repack_bqkv_k(const float* __restrict__ bq, const float* __restrict__ bk,
                              const float* __restrict__ bv, float* __restrict__ dst) {
  int idx = blockIdx.x * 256 + threadIdx.x;
  if (idx >= CL * 2304) return;
  int l = idx / 2304;
  int c = idx % 2304;
  int sec = c / CD;
  int within = c % CD;
  int h = within / CDH;
  int e = within % CDH;
  const float* B = (sec == 0) ? bq : ((sec == 1) ? bk : bv);
  float v = B[((size_t)l * CH + h) * CDH + e];
  if (sec == 0) v *= QSCALE;
  dst[idx] = v;
}

extern "C" void kernel_launch(void* const* d_in, const int* in_sizes, int n_in,
                              void* d_out, int out_size, void* d_ws, size_t ws_size,
                              hipStream_t stream) {
  (void)in_sizes; (void)n_in; (void)out_size; (void)ws_size;
  const float* X = (const float*)d_in[0];
  const int* MSK = (const int*)d_in[1];
  const float* Wq = (const float*)d_in[2];
  const float* bq = (const float*)d_in[3];
  const float* Wk = (const float*)d_in[4];
  const float* bk = (const float*)d_in[5];
  const float* Wv = (const float*)d_in[6];
  const float* bv = (const float*)d_in[7];
  const float* Wo = (const float*)d_in[8];
  const float* bo = (const float*)d_in[9];
  const float* lng = (const float*)d_in[10];
  const float* lnb = (const float*)d_in[11];
  const float* W1 = (const float*)d_in[12];
  const float* b1 = (const float*)d_in[13];
  const float* W2 = (const float*)d_in[14];
  const float* b2 = (const float*)d_in[15];

  char* base = (char*)d_ws;
  size_t off = 0;
  auto alloc = [&](size_t bytes) {
    char* p = base + off;
    off = (off + bytes + 255) & ~(size_t)255;
    return p;
  };
  ushort* wqkv_t = (ushort*)alloc((size_t)CL * 2304 * CD * 2);
  ushort* wo_t = (ushort*)alloc((size_t)CL * CD * CD * 2);
  ushort* w1_t = (ushort*)alloc((size_t)CL * CF * CD * 2);
  ushort* w2_t = (ushort*)alloc((size_t)CL * CD * CF * 2);
  float* bqkv = (float*)alloc((size_t)CL * 2304 * 4);
  ushort* xb = (ushort*)alloc((size_t)CB * CT * CD * 2);
  ushort* qkv = (ushort*)alloc((size_t)CB * CT * 2304 * 2);   // 18.87 MB
  ushort* vt = (ushort*)alloc((size_t)CB * CH * CDH * CT * 2); // 6.29 MB
  unsigned* mbits = (unsigned*)alloc((size_t)CT * 64 * 4);
  unsigned char* rowall = (unsigned char*)alloc((size_t)CT);
  ushort* attno = (ushort*)alloc((size_t)CB * CT * CD * 2);
  float* xattn = (float*)alloc((size_t)CB * CT * CD * 4);
  float* xf = (float*)alloc((size_t)CB * CT * CD * 4);
  ushort* hln = (ushort*)alloc((size_t)CB * CT * CD * 2);
  ushort* gbuf = (ushort*)alloc((size_t)CB * CT * CF * 2);
  // FFN2 split-K partials (25.17 MB) alias dead qkv+vt (dead after flash,
  // rewritten next layer after reduce2 consumed the partials)
  float* part = (float*)qkv;

  const int BT_ = CB * CT;  // 4096 rows

  // ---- one-time weight repacks (coalesced tiled transposes) ----
  for (int l = 0; l < CL; ++l) {
    tcvt_k<<<dim3(CDH / 32, CD / 32, CH), 256, 0, stream>>>(
        Wq + (size_t)l * CH * CD * CDH, (size_t)CD * CDH,
        wqkv_t + (size_t)l * 2304 * CD + 0 * CD * CD, (size_t)CDH * CD,
        CD, CDH, QSCALE);
    tcvt_k<<<dim3(CDH / 32, CD / 32, CH), 256, 0, stream>>>(
        Wk + (size_t)l * CH * CD * CDH, (size_t)CD * CDH,
        wqkv_t + (size_t)l * 2304 * CD + 1 * CD * CD, (size_t)CDH * CD,
        CD, CDH, 1.0f);
    tcvt_k<<<dim3(CDH / 32, CD / 32, CH), 256, 0, stream>>>(
        Wv + (size_t)l * CH * CD * CDH, (size_t)CD * CDH,
        wqkv_t + (size_t)l * 2304 * CD + 2 * CD * CD, (size_t)CDH * CD,
        CD, CDH, 1.0f);
  }
  tcvt_k<<<dim3(CD / 32, CD / 32, CL), 256, 0, stream>>>(
      Wo, (size_t)CD * CD, wo_t, (size_t)CD * CD, CD, CD, 1.0f);
  tcvt_k<<<dim3(CF / 32, CD / 32, CL), 256, 0, stream>>>(
      W1, (size_t)CD * CF, w1_t, (size_t)CF * CD, CD, CF, 1.0f);
  tcvt_k<<<dim3(CD / 32, CF / 32, CL), 256, 0, stream>>>(
      W2, (size_t)CF * CD, w2_t, (size_t)CD * CF, CF, CD, 1.0f);
  {
    int n = CL * 2304;
    repack_bqkv_k<<<(n + 255) / 256, 256, 0, stream>>>(bq, bk, bv, bqkv);
  }
  maskrow_k<<<CT / 4, 256, 0, stream>>>(MSK, mbits, rowall);

  // layer-0 input -> bf16 (layer 1 gets it fused from FFN2's reduce)
  {
    int n4 = BT_ * CD / 4;
    f32_to_bf16_k<<<(n4 + 255) / 256, 256, 0, stream>>>(X, xb, n4);
  }

  for (int l = 0; l < CL; ++l) {
    const float* xcur = (l == 0) ? X : xf;
    // QKV projection + FUSED V-transpose (BN=256): Q/K -> qkv, V -> vt
    gemm_k<EPI_QKV, 256><<<dim3(2304 / 256, BT_ / 128), 256, 0, stream>>>(
        xb, CD, wqkv_t + (size_t)l * 2304 * CD, CD, qkv, 2304, CD,
        bqkv + (size_t)l * 2304, nullptr, vt);
    // fused flash attention
    flash_k<<<dim3(CT / 64, CBH), 256, 0, stream>>>(qkv, vt, mbits, rowall, attno);
    // output projection + bias + residual -> xattn (fp32), BN=128 (grid fill)
    gemm_k<EPI_BIAS_RES_F32, 128><<<dim3(CD / 128, BT_ / 128), 256, 0, stream>>>(
        attno, CD, wo_t + (size_t)l * CD * CD, CD, xattn, CD, CD,
        bo + (size_t)l * CD, xcur, nullptr);
    // layernorm -> hln bf16
    ln_k<<<BT_, 256, 0, stream>>>(xattn, hln, lng + (size_t)l * CD, lnb + (size_t)l * CD);
    // FFN1 + bias + gelu -> gbuf bf16 (BN=256)
    gemm_k<EPI_BIAS_GELU_BF16, 256><<<dim3(CF / 256, BT_ / 128), 256, 0, stream>>>(
        hln, CD, w1_t + (size_t)l * CF * CD, CD, gbuf, CF, CD,
        b1 + (size_t)l * CF, nullptr, nullptr);
    // FFN2 split-K=2 -> f32 partials (BN=128, grid fill via z)
    gemm_k<EPI_PART_F32, 128><<<dim3(CD / 128, BT_ / 128, 2), 256, 0, stream>>>(
        gbuf, CF, w2_t + (size_t)l * CD * CF, CF, part, CD, CF / 2,
        nullptr, nullptr, nullptr);
    // reduce partials + bias + residual -> xf (+ bf16 xb) or d_out
    const int nred = BT_ * CD / 4 / 256;  // 3072 blocks
    if (l == CL - 1) {
      reduce2_k<false><<<nred, 256, 0, stream>>>(part, b2 + (size_t)l * CD, xattn,
                                                 (float*)d_out, nullptr);
    } else {
      reduce2_k<true><<<nred, 256, 0, stream>>>(part, b2 + (size_t)l * CD, xattn,
                                                xf, xb);
    }
  }
}

// Round 15
// 401.756 us; speedup vs baseline: 1.2901x; 1.2901x over previous
//
#include <hip/hip_runtime.h>
#include <math.h>

// Problem constants
#define CL 2
#define CH 12
#define CD 768
#define CDH 64
#define CF 3072
#define CB 2
#define CT 2048
#define CBH (CB * CH)
#define CBTCD ((size_t)CB * CT * CD)

typedef __bf16 bf16x8 __attribute__((ext_vector_type(8)));
typedef float f32x4 __attribute__((ext_vector_type(4)));
typedef short s16x4 __attribute__((ext_vector_type(4)));
typedef ushort u16x4 __attribute__((ext_vector_type(4)));

// 0.125 * log2(e): folded into Wq/bq so QK^T lands in exp2 domain
#define QSCALE 0.18033688011112042f

__device__ __forceinline__ ushort f2bf(float f) {
  return __builtin_bit_cast(ushort, (__bf16)f);
}

__device__ __forceinline__ float fexp2(float x) {
  float r;
  asm volatile("v_exp_f32 %0, %1" : "=v"(r) : "v"(x));
  return r;
}

__device__ __forceinline__ float wred_sum(float v) {
#pragma unroll
  for (int o = 32; o > 0; o >>= 1) v += __shfl_xor(v, o);
  return v;
}

// async global->LDS, 16B per lane. LDS dest = wave-uniform base + lane*16.
__device__ __forceinline__ void gload16(const ushort* g, ushort* l) {
  __builtin_amdgcn_global_load_lds(
      (const __attribute__((address_space(1))) unsigned int*)g,
      (__attribute__((address_space(3))) unsigned int*)l, 16, 0, 0);
}

// ---------------- GEMM (m97 structure, 3-buffer 1-deep prefetch,
//                  SINGLE barrier per K-step, XCD swizzle) ----------------
// C(MxN) = A(MxK) @ B, A bf16 row-major (lda), B stored (N x K) row-major (ldb).
// REQUIRES: M % 128 == 0, N % 128 == 0, K % 64 == 0, (gridX*gridY) % 8 == 0.
// Single-barrier safety (N buffers, D-deep prefetch): removable trailing
// barrier iff D+1 != 0 (mod N). Here N=3, D=1 -> 2 !≡ 0 (mod 3): a wave one
// barrier ahead stages buf (kt+2)%3 while the slowest wave computes buf
// kt%3 — always distinct. Own vmcnt(4) before the barrier retires this
// wave's stage(kt) loads; the barrier publishes all quarters.
enum { EPI_BF16 = 1, EPI_BIAS_BF16 = 2, EPI_BIAS_GELU_BF16 = 3, EPI_BIAS_RES_F32 = 4, EPI_BIAS_RES_F32_BF16 = 5, EPI_PART_F32 = 6, EPI_QKV = 7 };

template <int EPI>
__global__ __launch_bounds__(256) void gemm_k(
    const ushort* __restrict__ A, int lda,
    const ushort* __restrict__ B, int ldb,
    void* __restrict__ Cv, int ldc,
    int K,
    const float* __restrict__ bias,
    const float* __restrict__ res,
    ushort* __restrict__ C2) {
  __shared__ ushort As[3][128 * 32];
  __shared__ ushort Bs[3][128 * 32];
  const int tid = threadIdx.x;
  const int lane = tid & 63;
  const int wave = tid >> 6;
  const int wm = (wave >> 1) * 64;
  const int wn = (wave & 1) * 64;

  // bijective XCD swizzle (gridX*gridY multiple of 8)
  const int gx = gridDim.x;
  const int nwg = gx * gridDim.y;
  int wgid = blockIdx.y * gx + blockIdx.x;
  const int cpx = nwg >> 3;
  wgid = (wgid & 7) * cpx + (wgid >> 3);
  const int m0 = (wgid / gx) * 128;
  const int n0 = (wgid % gx) * 128;

  const int lr = lane & 15;
  const int lg = lane >> 4;
  f32x4 acc[4][4] = {};

  const int kz = blockIdx.z * K;  // K-split offset (0 for non-split launches)
  const ushort* pa = A + (size_t)(m0 + (tid >> 2)) * lda + (tid & 3) * 8 + kz;
  const ushort* pb = B + (size_t)(n0 + (tid >> 2)) * ldb + (tid & 3) * 8 + kz;

  auto stage = [&](int buf, int k0) {
#pragma unroll
    for (int p = 0; p < 2; ++p) {
      gload16(pa + (size_t)p * 64 * lda + k0, &As[buf][wave * 512 + p * 2048]);
      gload16(pb + (size_t)p * 64 * ldb + k0, &Bs[buf][wave * 512 + p * 2048]);
    }
  };

  const int nt = K >> 5;
  stage(0, 0);
  for (int kt = 0; kt < nt; ++kt) {
    const int cur = kt % 3;
    if (kt + 1 < nt) {
      stage((kt + 1) % 3, (kt + 1) << 5);
      asm volatile("s_waitcnt vmcnt(4)" ::: "memory");
    } else {
      asm volatile("s_waitcnt vmcnt(0)" ::: "memory");
    }
    __builtin_amdgcn_s_barrier();
    __builtin_amdgcn_sched_barrier(0);

    bf16x8 af[4], bfr[4];
#pragma unroll
    for (int f = 0; f < 4; ++f) af[f] = *(const bf16x8*)(&As[cur][(wm + f * 16 + lr) * 32 + lg * 8]);
#pragma unroll
    for (int f = 0; f < 4; ++f) bfr[f] = *(const bf16x8*)(&Bs[cur][(wn + f * 16 + lr) * 32 + lg * 8]);
#pragma unroll
    for (int i = 0; i < 4; ++i)
#pragma unroll
      for (int j = 0; j < 4; ++j)
        acc[i][j] = __builtin_amdgcn_mfma_f32_16x16x32_bf16(af[i], bfr[j], acc[i][j], 0, 0, 0);
  }

  // epilogue: lane holds D[row=(lane>>4)*4+r][col=lane&15] per frag
  const int cr0 = lg * 4;
#pragma unroll
  for (int i = 0; i < 4; ++i) {
#pragma unroll
    for (int j = 0; j < 4; ++j) {
      int col = n0 + wn + j * 16 + lr;
      if constexpr (EPI == EPI_QKV) {
        const int cbase = n0 + wn + j * 16;  // frag col base (uniform)
        const int row0 = m0 + wm + i * 16 + cr0;
        float bcol = bias[col];
        if (cbase >= 2 * CD) {
          // V section: write ONLY transposed vt[bh][e][t], 4 tokens = u16x4
          const int bb = row0 >> 11;          // row0 / CT
          const int t0 = row0 & (CT - 1);
          const int hh = (cbase - 2 * CD) >> 6;
          const int ee = ((cbase - 2 * CD) & 63) + lr;
          u16x4 o;
#pragma unroll
          for (int r = 0; r < 4; ++r) o[r] = f2bf(acc[i][j][r] + bcol);
          *(u16x4*)(C2 + ((size_t)(bb * CH + hh) * 64 + ee) * CT + t0) = o;
        } else {
#pragma unroll
          for (int r = 0; r < 4; ++r)
            ((ushort*)Cv)[(size_t)(row0 + r) * ldc + col] = f2bf(acc[i][j][r] + bcol);
        }
        continue;
      }
#pragma unroll
      for (int r = 0; r < 4; ++r) {
        int row = m0 + wm + i * 16 + cr0 + r;
        float val = acc[i][j][r];
        size_t offc = (size_t)row * ldc + col;
        if constexpr (EPI == EPI_BF16) {
          ((ushort*)Cv)[offc] = f2bf(val);
        } else if constexpr (EPI == EPI_BIAS_BF16) {
          ((ushort*)Cv)[offc] = f2bf(val + bias[col]);
        } else if constexpr (EPI == EPI_BIAS_GELU_BF16) {
          float x = val + bias[col];
          float gel = 0.5f * x * (1.0f + erff(x * 0.70710678118654752f));
          ((ushort*)Cv)[offc] = f2bf(gel);
        } else if constexpr (EPI == EPI_BIAS_RES_F32) {
          ((float*)Cv)[offc] = val + bias[col] + res[offc];
        } else if constexpr (EPI == EPI_PART_F32) {
          ((float*)Cv)[blockIdx.z * CBTCD + offc] = val;
        } else if constexpr (EPI == EPI_BIAS_RES_F32_BF16) {
          float o = val + bias[col] + res[offc];
          ((float*)Cv)[offc] = o;
          C2[offc] = f2bf(o);
        }
      }
    }
  }
}

// ---------------- split-K reduce: out = p0 + p1 + bias + res ----------------
template <bool DUAL>
__global__ __launch_bounds__(256) void reduce2_k(const float* __restrict__ part,
                                                 const float* __restrict__ bias,
                                                 const float* __restrict__ res,
                                                 float* __restrict__ outf,
                                                 ushort* __restrict__ outb) {
  int i = blockIdx.x * 256 + threadIdx.x;  // float4 index over 4096x768
  float4 p0 = ((const float4*)part)[i];
  float4 p1 = ((const float4*)(part + CBTCD))[i];
  float4 rr = ((const float4*)res)[i];
  int col = (i * 4) % CD;
  float4 bb = *(const float4*)(bias + col);
  float4 o;
  o.x = p0.x + p1.x + rr.x + bb.x;
  o.y = p0.y + p1.y + rr.y + bb.y;
  o.z = p0.z + p1.z + rr.z + bb.z;
  o.w = p0.w + p1.w + rr.w + bb.w;
  ((float4*)outf)[i] = o;
  if constexpr (DUAL) {
    ushort4 u;
    u.x = f2bf(o.x); u.y = f2bf(o.y); u.z = f2bf(o.z); u.w = f2bf(o.w);
    ((ushort4*)outb)[i] = u;
  }
}

// ---------------- flash attention (swapped QK^T, in-register softmax,
//   T14 reg-prefetch, dbuf LDS, 1 barrier/tile, XOR-swizzled LDS slots,
//   ZERO-SHFL hot path + st-hoisted-above-compute) ----------------
// grid: (CT/64, CB*CH). block 256 = 4 waves; each wave owns 16 q rows (q=lr).
__global__ __launch_bounds__(256) void flash_k(const ushort* __restrict__ qkv,
                                               const ushort* __restrict__ vt,
                                               const unsigned* __restrict__ mbits,
                                               const unsigned char* __restrict__ rowall,
                                               ushort* __restrict__ out) {
  const int q0 = blockIdx.x * 64;
  const int bh = blockIdx.y;
  const int b = bh / CH, h = bh % CH;
  const int tid = threadIdx.x;
  const int lane = tid & 63;
  const int wave = tid >> 6;
  const int lr = lane & 15;
  const int lg = lane >> 4;

  __shared__ ushort Ks[2][64 * 64];   // [buf][kv][d] swizzled slots
  __shared__ ushort Vt[2][64 * 64];   // [buf][e][kv] swizzled slots

  const int qg = q0 + wave * 16 + lr;  // this lane's q row
  const ushort* qrow = qkv + ((size_t)(b * CT) + qg) * 2304 + h * CDH;
  bf16x8 aq0 = *(const bf16x8*)(qrow + lg * 8);
  bf16x8 aq1 = *(const bf16x8*)(qrow + 32 + lg * 8);

  f32x4 acc[4] = {};              // O^T frags: acc[jj][r] = O^T[jj*16+lg*4+r][q=lr]
  float m_run = -1e30f, l_run = 0.f;  // l_run: per-LANE partial (mates share m)
  const bool am = rowall[qg] != 0;    // row fully unmasked -> skip mask work

  const ushort* kbase = qkv + (size_t)(b * CT) * 2304 + CD + h * CDH;
  const ushort* vbase = vt + (size_t)bh * 64 * CT;

  // staging: rows r0/r1 (r1 = r0+32 -> same (row&7)), global col cc LINEAR,
  // LDS slot swizzled: ssl = (slot ^ (r0&7)) * 8 elements
  const int r0 = tid >> 3, r1 = 32 + (tid >> 3), cc = (tid & 7) * 8;
  const int ssl = (((tid & 7) ^ (r0 & 7)) * 8);

  // swizzled READ offsets (elements)
  const int koff0 = ((lg ^ (lr & 7)) * 8);        // K d-half 0: slot lg
  const int koff1 = (((4 + lg) ^ (lr & 7)) * 8);  // K d-half 1: slot 4+lg
  int voff[4];
#pragma unroll
  for (int j = 0; j < 4; ++j)
    voff[j] = (((2 * j + (lg >> 1)) ^ (lr & 7)) * 8) + (lg & 1) * 4;

  auto ld = [&](int kv0, bf16x8& k0, bf16x8& k1, bf16x8& v0, bf16x8& v1) {
    k0 = *(const bf16x8*)(kbase + (size_t)(kv0 + r0) * 2304 + cc);
    k1 = *(const bf16x8*)(kbase + (size_t)(kv0 + r1) * 2304 + cc);
    v0 = *(const bf16x8*)(vbase + (size_t)r0 * CT + kv0 + cc);
    v1 = *(const bf16x8*)(vbase + (size_t)r1 * CT + kv0 + cc);
  };
  auto st = [&](int buf, bf16x8 k0, bf16x8 k1, bf16x8 v0, bf16x8 v1) {
    *(bf16x8*)(&Ks[buf][r0 * 64 + ssl]) = k0;
    *(bf16x8*)(&Ks[buf][r1 * 64 + ssl]) = k1;
    *(bf16x8*)(&Vt[buf][r0 * 64 + ssl]) = v0;
    *(bf16x8*)(&Vt[buf][r1 * 64 + ssl]) = v1;
  };
  // lgkmcnt-only barrier: ds_writes visible, global prefetch stays in flight
  auto bar = [&]() {
    asm volatile("s_waitcnt lgkmcnt(0)" ::: "memory");
    __builtin_amdgcn_s_barrier();
    __builtin_amdgcn_sched_barrier(0);
  };

  auto compute = [&](int kv0, int buf) {
    // S^T = K Q^T (4 tiles of 16 kv x 16 q), already exp2-domain scaled
    f32x4 stt[4];
    __builtin_amdgcn_s_setprio(1);
#pragma unroll
    for (int j = 0; j < 4; ++j) {
      bf16x8 kf0 = *(const bf16x8*)(&Ks[buf][(j * 16 + lr) * 64 + koff0]);
      bf16x8 kf1 = *(const bf16x8*)(&Ks[buf][(j * 16 + lr) * 64 + koff1]);
      f32x4 t = {};
      t = __builtin_amdgcn_mfma_f32_16x16x32_bf16(kf0, aq0, t, 0, 0, 0);
      t = __builtin_amdgcn_mfma_f32_16x16x32_bf16(kf1, aq1, t, 0, 0, 0);
      stt[j] = t;
    }
    __builtin_amdgcn_s_setprio(0);

    // mask + IN-LANE max over this lane's 16 kv values (rowall hot path)
    float tmax = -INFINITY;
    if (am) {
#pragma unroll
      for (int j = 0; j < 4; ++j)
#pragma unroll
        for (int r = 0; r < 4; ++r) tmax = fmaxf(tmax, stt[j][r]);
    } else {
      unsigned w0 = mbits[(size_t)qg * 64 + (kv0 >> 5)];
      unsigned w1 = mbits[(size_t)qg * 64 + (kv0 >> 5) + 1];
#pragma unroll
      for (int j = 0; j < 4; ++j) {
        unsigned w = (j < 2) ? w0 : w1;
#pragma unroll
        for (int r = 0; r < 4; ++r) {
          int bit = (j * 16 + lg * 4 + r) & 31;
          if (((w >> bit) & 1u) == 0u) stt[j][r] = -INFINITY;
          tmax = fmaxf(tmax, stt[j][r]);
        }
      }
    }

    // defer-rescale (T13) with ZERO-SHFL hot path: __any over LANE-local max
    // is equivalent to testing the row max. The cross-lane max (2 shfls)
    // runs only inside the rescale branch where it is actually needed.
    if (__any(tmax - m_run > 8.0f)) {
      tmax = fmaxf(tmax, __shfl_xor(tmax, 16));
      tmax = fmaxf(tmax, __shfl_xor(tmax, 32));
      float mnew = fmaxf(m_run, tmax);
      float sc = fexp2(m_run - mnew);
      m_run = mnew;
      l_run *= sc;
#pragma unroll
      for (int jj = 0; jj < 4; ++jj) {
        acc[jj][0] *= sc; acc[jj][1] *= sc; acc[jj][2] *= sc; acc[jj][3] *= sc;
      }
    }

    s16x4 pf[4];
#pragma unroll
    for (int j = 0; j < 4; ++j) {
      s16x4 pv;
#pragma unroll
      for (int r = 0; r < 4; ++r) {
        float p = fexp2(stt[j][r] - m_run);
        l_run += p;
        pv[r] = (short)f2bf(p);
      }
      pf[j] = pv;
    }

    // PV: O^T[e][q] += V^T[e][kv] * P^T[kv][q], 16x16x16 mfma, K=16 per j
    __builtin_amdgcn_s_setprio(1);
#pragma unroll
    for (int jj = 0; jj < 4; ++jj) {
#pragma unroll
      for (int j = 0; j < 4; ++j) {
        s16x4 vf = *(const s16x4*)(&Vt[buf][(jj * 16 + lr) * 64 + voff[j]]);
        acc[jj] = __builtin_amdgcn_mfma_f32_16x16x16bf16_1k(vf, pf[j], acc[jj], 0, 0, 0);
      }
    }
    __builtin_amdgcn_s_setprio(0);
  };

  // main loop: dbuf LDS, ONE barrier per tile, reg ping-pong X/Y prefetch.
  // st() is hoisted ABOVE compute() — the ds_writes drain under the MFMA
  // cluster. Safety: each st(buf) still sits after the barrier that retired
  // buf's last reader (st(1) after loop-end bar; st(0) after mid bar).
  bf16x8 kx0, kx1, vx0, vx1, ky0, ky1, vy0, vy1;
  ld(0, kx0, kx1, vx0, vx1);
  ld(64, ky0, ky1, vy0, vy1);
  st(0, kx0, kx1, vx0, vx1);
  bar();
  for (int t = 0; t < 32; t += 2) {
    if (t + 2 < 32) ld((t + 2) * 64, kx0, kx1, vx0, vx1);
    st(1, ky0, ky1, vy0, vy1);
    compute(t * 64, 0);
    bar();
    if (t + 3 < 32) ld((t + 3) * 64, ky0, ky1, vy0, vy1);
    if (t + 2 < 32) st(0, kx0, kx1, vx0, vx1);
    compute((t + 1) * 64, 1);
    if (t + 2 < 32) bar();
  }

  // final cross-lane reduce of per-lane l partials (mates lr, +16, +32, +48)
  l_run += __shfl_xor(l_run, 16);
  l_run += __shfl_xor(l_run, 32);

  // write O: lane holds O^T[e=jj*16+lg*4+r][q=lr] -> out[qg][h*64+e]
  float inv = 1.0f / l_run;
  const int orow = b * CT + qg;
#pragma unroll
  for (int jj = 0; jj < 4; ++jj) {
    u16x4 o;
#pragma unroll
    for (int r = 0; r < 4; ++r) o[r] = f2bf(acc[jj][r] * inv);
    *(u16x4*)(out + (size_t)orow * CD + h * CDH + jj * 16 + lg * 4) = o;
  }
}

// ---------------- mask -> bitmask + per-row all-ones flag (fused) ----------
// block 256 = 4 waves; wave w handles row t = blockIdx.x*4 + w, lane = word.
__global__ __launch_bounds__(256) void maskrow_k(const int* __restrict__ mask,
                                                 unsigned* __restrict__ mbits,
                                                 unsigned char* __restrict__ rowall) {
  const int lane = threadIdx.x & 63;
  const int t = blockIdx.x * 4 + (threadIdx.x >> 6);
  const int* mp = mask + (size_t)t * CT + lane * 32;
  unsigned bits = 0;
#pragma unroll
  for (int j = 0; j < 32; ++j) bits |= (mp[j] != 0 ? 1u : 0u) << j;
  mbits[(size_t)t * 64 + lane] = bits;
  unsigned long long vote = __ballot(bits == 0xFFFFFFFFu);
  if (lane == 0) rowall[t] = (vote == ~0ull) ? 1 : 0;
}

// ---------------- layernorm ----------------
__global__ __launch_bounds__(256) void ln_k(const float* __restrict__ X,
                                            ushort* __restrict__ H,
                                            const float* __restrict__ g,
                                            const float* __restrict__ b) {
  const int t = blockIdx.x;
  const int tid = threadIdx.x;
  const float* row = X + (size_t)t * CD;
  float x0 = row[tid], x1 = row[tid + 256], x2 = row[tid + 512];
  float s = wred_sum(x0 + x1 + x2);
  __shared__ float sh[4], sh2[4];
  if ((tid & 63) == 0) sh[tid >> 6] = s;
  __syncthreads();
  float mu = (sh[0] + sh[1] + sh[2] + sh[3]) * (1.0f / 768.0f);
  float d0 = x0 - mu, d1 = x1 - mu, d2 = x2 - mu;
  float vs = wred_sum(d0 * d0 + d1 * d1 + d2 * d2);
  if ((tid & 63) == 0) sh2[tid >> 6] = vs;
  __syncthreads();
  float var = (sh2[0] + sh2[1] + sh2[2] + sh2[3]) * (1.0f / 768.0f);
  float r = 1.0f / sqrtf(var + 1e-5f);
  H[(size_t)t * CD + tid] = f2bf(d0 * r * g[tid] + b[tid]);
  H[(size_t)t * CD + tid + 256] = f2bf(d1 * r * g[tid + 256] + b[tid + 256]);
  H[(size_t)t * CD + tid + 512] = f2bf(d2 * r * g[tid + 512] + b[tid + 512]);
}

// ---------------- conversions / repacks ----------------
__global__ void f32_to_bf16_k(const float* __restrict__ in, ushort* __restrict__ out, int n4) {
  int i = blockIdx.x * 256 + threadIdx.x;
  if (i >= n4) return;
  float4 f = *(const float4*)(in + (size_t)i * 4);
  ushort4 u;
  u.x = f2bf(f.x); u.y = f2bf(f.y); u.z = f2bf(f.z); u.w = f2bf(f.w);
  *(ushort4*)(out + (size_t)i * 4) = u;
}

// tiled transpose + f32->bf16: src (z batches, [R][C] f32, stride sbs) ->
// dst (z batches, [C][R] bf16, stride dbs). R, C multiples of 32.
__global__ __launch_bounds__(256) void tcvt_k(const float* __restrict__ src, size_t sbs,
                                              ushort* __restrict__ dst, size_t dbs,
                                              int R, int C, float scale) {
  __shared__ float t[32][33];
  const float* s = src + blockIdx.z * sbs;
  ushort* d = dst + blockIdx.z * dbs;
  const int tx = threadIdx.x & 31;
  const int ty4 = (threadIdx.x >> 5) * 4;
  const int r0 = blockIdx.y * 32, c0 = blockIdx.x * 32;
#pragma unroll
  for (int i = 0; i < 4; ++i) t[ty4 + i][tx] = s[(size_t)(r0 + ty4 + i) * C + c0 + tx];
  __syncthreads();
#pragma unroll
  for (int i = 0; i < 4; ++i)
    d[(size_t)(c0 + ty4 + i) * R + r0 + tx] = f2bf(t[tx][ty4 + i] * scale);
}

// bq/bk/bv (L,H,DH) -> bqkv (L, 2304) fp32; bq scaled by QSCALE
__global__ void repack_bqkv_k(const float* __restrict__ bq, const float* __restrict__ bk,
                              const float* __restrict__ bv, float* __restrict__ dst) {
  int idx = blockIdx.x * 256 + threadIdx.x;
  if (idx >= CL * 2304) return;
  int l = idx / 2304;
  int c = idx % 2304;
  int sec = c / CD;
  int within = c % CD;
  int h = within / CDH;
  int e = within % CDH;
  const float* B = (sec == 0) ? bq : ((sec == 1) ? bk : bv);
  float v = B[((size_t)l * CH + h) * CDH + e];
  if (sec == 0) v *= QSCALE;
  dst[idx] = v;
}

extern "C" void kernel_launch(void* const* d_in, const int* in_sizes, int n_in,
                              void* d_out, int out_size, void* d_ws, size_t ws_size,
                              hipStream_t stream) {
  (void)in_sizes; (void)n_in; (void)out_size; (void)ws_size;
  const float* X = (const float*)d_in[0];
  const int* MSK = (const int*)d_in[1];
  const float* Wq = (const float*)d_in[2];
  const float* bq = (const float*)d_in[3];
  const float* Wk = (const float*)d_in[4];
  const float* bk = (const float*)d_in[5];
  const float* Wv = (const float*)d_in[6];
  const float* bv = (const float*)d_in[7];
  const float* Wo = (const float*)d_in[8];
  const float* bo = (const float*)d_in[9];
  const float* lng = (const float*)d_in[10];
  const float* lnb = (const float*)d_in[11];
  const float* W1 = (const float*)d_in[12];
  const float* b1 = (const float*)d_in[13];
  const float* W2 = (const float*)d_in[14];
  const float* b2 = (const float*)d_in[15];

  char* base = (char*)d_ws;
  size_t off = 0;
  auto alloc = [&](size_t bytes) {
    char* p = base + off;
    off = (off + bytes + 255) & ~(size_t)255;
    return p;
  };
  ushort* wqkv_t = (ushort*)alloc((size_t)CL * 2304 * CD * 2);
  ushort* wo_t = (ushort*)alloc((size_t)CL * CD * CD * 2);
  ushort* w1_t = (ushort*)alloc((size_t)CL * CF * CD * 2);
  ushort* w2_t = (ushort*)alloc((size_t)CL * CD * CF * 2);
  float* bqkv = (float*)alloc((size_t)CL * 2304 * 4);
  ushort* xb = (ushort*)alloc((size_t)CB * CT * CD * 2);
  ushort* qkv = (ushort*)alloc((size_t)CB * CT * 2304 * 2);   // 18.87 MB
  ushort* vt = (ushort*)alloc((size_t)CB * CH * CDH * CT * 2); // 6.29 MB
  unsigned* mbits = (unsigned*)alloc((size_t)CT * 64 * 4);
  unsigned char* rowall = (unsigned char*)alloc((size_t)CT);
  ushort* attno = (ushort*)alloc((size_t)CB * CT * CD * 2);
  float* xattn = (float*)alloc((size_t)CB * CT * CD * 4);
  float* xf = (float*)alloc((size_t)CB * CT * CD * 4);
  ushort* hln = (ushort*)alloc((size_t)CB * CT * CD * 2);
  ushort* gbuf = (ushort*)alloc((size_t)CB * CT * CF * 2);
  // FFN2 split-K partials (25.17 MB) alias dead qkv+vt (dead after flash,
  // rewritten next layer after reduce2 consumed the partials)
  float* part = (float*)qkv;

  const int BT_ = CB * CT;  // 4096 rows

  // ---- one-time weight repacks (coalesced tiled transposes) ----
  for (int l = 0; l < CL; ++l) {
    tcvt_k<<<dim3(CDH / 32, CD / 32, CH), 256, 0, stream>>>(
        Wq + (size_t)l * CH * CD * CDH, (size_t)CD * CDH,
        wqkv_t + (size_t)l * 2304 * CD + 0 * CD * CD, (size_t)CDH * CD,
        CD, CDH, QSCALE);
    tcvt_k<<<dim3(CDH / 32, CD / 32, CH), 256, 0, stream>>>(
        Wk + (size_t)l * CH * CD * CDH, (size_t)CD * CDH,
        wqkv_t + (size_t)l * 2304 * CD + 1 * CD * CD, (size_t)CDH * CD,
        CD, CDH, 1.0f);
    tcvt_k<<<dim3(CDH / 32, CD / 32, CH), 256, 0, stream>>>(
        Wv + (size_t)l * CH * CD * CDH, (size_t)CD * CDH,
        wqkv_t + (size_t)l * 2304 * CD + 2 * CD * CD, (size_t)CDH * CD,
        CD, CDH, 1.0f);
  }
  tcvt_k<<<dim3(CD / 32, CD / 32, CL), 256, 0, stream>>>(
      Wo, (size_t)CD * CD, wo_t, (size_t)CD * CD, CD, CD, 1.0f);
  tcvt_k<<<dim3(CF / 32, CD / 32, CL), 256, 0, stream>>>(
      W1, (size_t)CD * CF, w1_t, (size_t)CF * CD, CD, CF, 1.0f);
  tcvt_k<<<dim3(CD / 32, CF / 32, CL), 256, 0, stream>>>(
      W2, (size_t)CF * CD, w2_t, (size_t)CD * CF, CF, CD, 1.0f);
  {
    int n = CL * 2304;
    repack_bqkv_k<<<(n + 255) / 256, 256, 0, stream>>>(bq, bk, bv, bqkv);
  }
  maskrow_k<<<CT / 4, 256, 0, stream>>>(MSK, mbits, rowall);

  // layer-0 input -> bf16 (layer 1 gets it fused from FFN2's reduce)
  {
    int n4 = BT_ * CD / 4;
    f32_to_bf16_k<<<(n4 + 255) / 256, 256, 0, stream>>>(X, xb, n4);
  }

  for (int l = 0; l < CL; ++l) {
    const float* xcur = (l == 0) ? X : xf;
    // QKV projection + FUSED V-transpose: Q/K -> qkv, V -> vt (bf16)
    gemm_k<EPI_QKV><<<dim3(2304 / 128, BT_ / 128), 256, 0, stream>>>(
        xb, CD, wqkv_t + (size_t)l * 2304 * CD, CD, qkv, 2304, CD,
        bqkv + (size_t)l * 2304, nullptr, vt);
    // fused flash attention
    flash_k<<<dim3(CT / 64, CBH), 256, 0, stream>>>(qkv, vt, mbits, rowall, attno);
    // output projection + bias + residual -> xattn (fp32)
    gemm_k<EPI_BIAS_RES_F32><<<dim3(CD / 128, BT_ / 128), 256, 0, stream>>>(
        attno, CD, wo_t + (size_t)l * CD * CD, CD, xattn, CD, CD,
        bo + (size_t)l * CD, xcur, nullptr);
    // layernorm -> hln bf16
    ln_k<<<BT_, 256, 0, stream>>>(xattn, hln, lng + (size_t)l * CD, lnb + (size_t)l * CD);
    // FFN1 + bias + gelu -> gbuf bf16
    gemm_k<EPI_BIAS_GELU_BF16><<<dim3(CF / 128, BT_ / 128), 256, 0, stream>>>(
        hln, CD, w1_t + (size_t)l * CF * CD, CD, gbuf, CF, CD,
        b1 + (size_t)l * CF, nullptr, nullptr);
    // FFN2 split-K=2 -> f32 partials (alias over dead qkv+vt)
    gemm_k<EPI_PART_F32><<<dim3(CD / 128, BT_ / 128, 2), 256, 0, stream>>>(
        gbuf, CF, w2_t + (size_t)l * CD * CF, CF, part, CD, CF / 2,
        nullptr, nullptr, nullptr);
    // reduce partials + bias + residual -> xf (+ bf16 xb) or d_out
    const int nred = BT_ * CD / 4 / 256;  // 3072 blocks
    if (l == CL - 1) {
      reduce2_k<false><<<nred, 256, 0, stream>>>(part, b2 + (size_t)l * CD, xattn,
                                                 (float*)d_out, nullptr);
    } else {
      reduce2_k<true><<<nred, 256, 0, stream>>>(part, b2 + (size_t)l * CD, xattn,
                                                xf, xb);
    }
  }
}